// Round 11
// baseline (127.639 us; speedup 1.0000x reference)
//
#include <hip/hip_runtime.h>
#include <hip/hip_cooperative_groups.h>

namespace cg = cooperative_groups;

// GAT layer: B=16, N=1024, IN_DIM=128, H=4, D=64, neg_slope=0.2
// Inputs fp32, adj int32, out fp32.
//
// R11 BISECT (R8/R10 failed identically at ~0.09 after multi-change rounds):
// k_prep + k_proj = R9 verbatim (HW-proven). k_attn = R7 verbatim EXCEPT the
// P-gen math: p = exp(lrelu(c+e)) == max(exp(c)exp(e), exp(.2c)exp(.2e))
// (exact identity: lrelu = max(s,.2s), exp monotone). F1=exp(e_dst),
// F2=exp(.2 e_dst) staged in LDS; E1/E2 per row. No j-split, no swizzle,
// 256-thr blocks — isolates factored-exp as the only new element.
// ws: hT @0 (8MB) | e_srcT @8388608 | e_dstT @8650752 | adjb @8912896 |
//     wT @9043968

#define B_  16
#define N_  1024
#define IND 128
#define H_  4
#define D_  64
#define NEG 0.2f

typedef __attribute__((ext_vector_type(8))) short short8;
typedef __attribute__((ext_vector_type(4))) float float4v;
typedef __attribute__((ext_vector_type(4))) unsigned int uint4v;
typedef __attribute__((ext_vector_type(2))) unsigned int uint2v;

union S8U4 { uint4v u; short8 s; };

static __device__ __forceinline__ unsigned short f2bf(float f) {
  unsigned int u = __float_as_uint(f);
  u += 0x7fffu + ((u >> 16) & 1u);
  return (unsigned short)(u >> 16);
}
static __device__ __forceinline__ unsigned pk_rne(float a, float b) {
  unsigned ua = __float_as_uint(a), ub = __float_as_uint(b);
  ua += 0x7fffu + ((ua >> 16) & 1u);
  ub += 0x7fffu + ((ub >> 16) & 1u);
  return __builtin_amdgcn_perm(ub, ua, 0x07060302);
}

// ---------------- prep: adj bit-pack + W transpose to bf16 (R9) ----------------
__global__ __launch_bounds__(256) void k_prep(const int* __restrict__ adj,
                                              const float* __restrict__ W,
                                              unsigned int* __restrict__ adjb,
                                              unsigned short* __restrict__ wT) {
  const int g = blockIdx.x, t = threadIdx.x, l = t & 63;
  if (g < 4096) {
    int f = g * 256 + t;
    unsigned long long m = __ballot(adj[f] > 0);
    if (l == 0) {
      adjb[f >> 5] = (unsigned int)m;
      adjb[(f >> 5) + 1] = (unsigned int)(m >> 32);
    }
  } else {
    int wb = g - 4096;
#pragma unroll
    for (int i = 0; i < 4; ++i) {
      int k = wb * 4 + i;
      wT[t * 128 + k] = f2bf(W[k * 256 + t]);    // wT[n][k]
    }
  }
}

// ---------------- projection: MFMA GEMM + e dots (R9, proven) ----------------
__global__ __launch_bounds__(256) void k_proj(const float* __restrict__ x,
                                              const float* __restrict__ a_src,
                                              const float* __restrict__ a_dst,
                                              const unsigned short* __restrict__ wT,
                                              unsigned short* __restrict__ hT,
                                              float* __restrict__ e_srcT,
                                              float* __restrict__ e_dstT) {
  __shared__ unsigned short wbuf[128 * 136];
  const int g = blockIdx.x, t = threadIdx.x;
  const int mt = g >> 1, nh = g & 1;
  const int w = t >> 6, l = t & 63, quad = l >> 4, ln = l & 15;

#pragma unroll
  for (int i = 0; i < 8; ++i) {
    int c = i * 256 + t;
    int n = c >> 4, k8 = c & 15;
    *reinterpret_cast<short8*>(&wbuf[n * 136 + k8 * 8]) =
        *reinterpret_cast<const short8*>(wT + (size_t)(nh * 128 + n) * 128 + k8 * 8);
  }
  __syncthreads();

  const int m0 = mt * 64 + w * 16;
  short8 afr[4];
#pragma unroll
  for (int ks = 0; ks < 4; ++ks) {
    const float* xp = x + (size_t)(m0 + ln) * IND + ks * 32 + quad * 8;
    float4v x0 = *reinterpret_cast<const float4v*>(xp);
    float4v x1 = *reinterpret_cast<const float4v*>(xp + 4);
    S8U4 cvt;
    cvt.u = (uint4v){pk_rne(x0.x, x0.y), pk_rne(x0.z, x0.w),
                     pk_rne(x1.x, x1.y), pk_rne(x1.z, x1.w)};
    afr[ks] = cvt.s;
  }

  float4v acc[8];
#pragma unroll
  for (int nf = 0; nf < 8; ++nf) acc[nf] = (float4v){0.f, 0.f, 0.f, 0.f};
#pragma unroll
  for (int nf = 0; nf < 8; ++nf) {
#pragma unroll
    for (int ks = 0; ks < 4; ++ks) {
      short8 bv = *reinterpret_cast<const short8*>(
          &wbuf[(nf * 16 + ln) * 136 + ks * 32 + quad * 8]);
      acc[nf] = __builtin_amdgcn_mfma_f32_16x16x32_bf16(afr[ks], bv, acc[nf], 0, 0, 0);
    }
  }

  const int m_base = m0 + quad * 4;
  const int b = m_base >> 10, nl = m_base & 1023;
  const int jb = nl >> 3, jo = nl & 7;
#pragma unroll
  for (int hl = 0; hl < 2; ++hl) {
    const int h = nh * 2 + hl;
    float es[4] = {0.f, 0.f, 0.f, 0.f}, ed[4] = {0.f, 0.f, 0.f, 0.f};
#pragma unroll
    for (int n4 = 0; n4 < 4; ++n4) {
      int nf = hl * 4 + n4;
      int col = nh * 128 + nf * 16 + ln;
      float asv = a_src[col], adv = a_dst[col];
#pragma unroll
      for (int r = 0; r < 4; ++r) { es[r] += acc[nf][r] * asv; ed[r] += acc[nf][r] * adv; }
      uint2v hv;
      hv.x = pk_rne(acc[nf][0], acc[nf][1]);
      hv.y = pk_rne(acc[nf][2], acc[nf][3]);
      int d = n4 * 16 + ln;
      *reinterpret_cast<uint2v*>(hT + ((size_t)(b * H_ + h) * 128 + jb) * 512 + d * 8 + jo) = hv;
    }
#pragma unroll
    for (int r = 0; r < 4; ++r) {
#pragma unroll
      for (int msk = 1; msk < 16; msk <<= 1) {
        es[r] += __shfl_xor(es[r], msk, 64);
        ed[r] += __shfl_xor(ed[r], msk, 64);
      }
    }
    if (ln == 0) {
#pragma unroll
      for (int r = 0; r < 4; ++r) {
        e_srcT[(b * H_ + h) * N_ + nl + r] = es[r];
        e_dstT[(b * H_ + h) * N_ + nl + r] = ed[r];
      }
    }
  }
}

// ------ attention: R7 structure, factored-exp (max identity) P-gen ------
__global__ __launch_bounds__(256) void k_attn(const unsigned short* __restrict__ hT,
                                              const float* __restrict__ e_srcT,
                                              const float* __restrict__ e_dstT,
                                              const unsigned int* __restrict__ adjb,
                                              float* __restrict__ out) {
  __shared__ float F1[H_][N_];                   // exp(e_dst)      16 KB
  __shared__ float F2[H_][N_];                   // exp(0.2 e_dst)  16 KB
  __shared__ float es_lds[H_][32];               // 512 B
  __shared__ unsigned int adj_lds[32 * 33];      // 4.2 KB padded

  const int t = threadIdx.x;
  const int w = t >> 6;                          // head = wave
  const int l = t & 63;
  const int quad = l >> 4;
  const int ln = l & 15;
  const int b = blockIdx.x >> 5;                 // 512 blocks: 16 b * 32 i-tiles
  const int i0 = (blockIdx.x & 31) * 32;

#pragma unroll
  for (int q = 0; q < 4; ++q) {
    int idx = q * 256 + t;
    int r = idx >> 5, c2 = idx & 31;
    adj_lds[r * 33 + c2] = adjb[(i0 + r) * 32 + c2];
  }
  // stage F1/F2 for all heads (each thread: 8 j's x 2 passes)
#pragma unroll
  for (int q = 0; q < 2; ++q) {
    int idx = q * 256 + t;                       // 0..511
    int hidx = idx >> 7, j = (idx & 127) * 8;
    const float* ep = e_dstT + (size_t)(b * H_ + hidx) * N_ + j;
    float4v e0 = *reinterpret_cast<const float4v*>(ep);
    float4v e1 = *reinterpret_cast<const float4v*>(ep + 4);
    *reinterpret_cast<float4v*>(&F1[hidx][j]) =
        (float4v){__expf(e0.x), __expf(e0.y), __expf(e0.z), __expf(e0.w)};
    *reinterpret_cast<float4v*>(&F1[hidx][j + 4]) =
        (float4v){__expf(e1.x), __expf(e1.y), __expf(e1.z), __expf(e1.w)};
    *reinterpret_cast<float4v*>(&F2[hidx][j]) =
        (float4v){__expf(NEG * e0.x), __expf(NEG * e0.y), __expf(NEG * e0.z), __expf(NEG * e0.w)};
    *reinterpret_cast<float4v*>(&F2[hidx][j + 4]) =
        (float4v){__expf(NEG * e1.x), __expf(NEG * e1.y), __expf(NEG * e1.z), __expf(NEG * e1.w)};
  }
  if (l < 32) es_lds[w][l] = e_srcT[(size_t)(b * H_ + w) * N_ + i0 + l];
  __syncthreads();

  // per-row-half constants
  float E1[2], E2[2];
#pragma unroll
  for (int it = 0; it < 2; ++it) {
    float cc = es_lds[w][it * 16 + ln];
    E1[it] = __expf(cc);
    E2[it] = __expf(NEG * cc);
  }

  const unsigned short* slab = hT + (size_t)(b * H_ + w) * 65536;
  const int doff = (quad * 512) + ln * 8;
  float4v acc[2][4];
#pragma unroll
  for (int it = 0; it < 2; ++it)
#pragma unroll
    for (int dt = 0; dt < 4; ++dt) acc[it][dt] = (float4v){0.f, 0.f, 0.f, 0.f};
  float ds[2] = {0.f, 0.f};

  for (int j0 = 0; j0 < N_; j0 += 32) {
    const float* f1p = &F1[w][j0 + quad * 8];
    const float* f2p = &F2[w][j0 + quad * 8];
    float4v f1a = *reinterpret_cast<const float4v*>(f1p);
    float4v f1b = *reinterpret_cast<const float4v*>(f1p + 4);
    float4v f2a = *reinterpret_cast<const float4v*>(f2p);
    float4v f2b = *reinterpret_cast<const float4v*>(f2p + 4);
    float f1[8] = {f1a.x, f1a.y, f1a.z, f1a.w, f1b.x, f1b.y, f1b.z, f1b.w};
    float f2[8] = {f2a.x, f2a.y, f2a.z, f2a.w, f2b.x, f2b.y, f2b.z, f2b.w};
    unsigned int aw[2];
#pragma unroll
    for (int it = 0; it < 2; ++it) aw[it] = adj_lds[(it * 16 + ln) * 33 + (j0 >> 5)];
    short8 afr[2];
#pragma unroll
    for (int it = 0; it < 2; ++it) {
#pragma unroll
      for (int jj = 0; jj < 8; ++jj) {
        // exp(lrelu(c+e)) = max(exp(c)exp(e), exp(.2c)exp(.2e)) — exact
        float p = fmaxf(E1[it] * f1[jj], E2[it] * f2[jj]);
        p = ((aw[it] >> (quad * 8 + jj)) & 1u) ? p : 0.f;
        ds[it] += p;
        afr[it][jj] = (short)f2bf(p);
      }
    }
    const unsigned short* jbase = slab + (size_t)(j0 >> 3) * 512;
#pragma unroll
    for (int dt = 0; dt < 4; ++dt) {
      short8 bv = *reinterpret_cast<const short8*>(jbase + doff + dt * 128);
#pragma unroll
      for (int it = 0; it < 2; ++it)
        acc[it][dt] = __builtin_amdgcn_mfma_f32_16x16x32_bf16(afr[it], bv, acc[it][dt], 0, 0, 0);
    }
  }

  float inv[2][4];
#pragma unroll
  for (int it = 0; it < 2; ++it) {
    float d2 = ds[it] + __shfl_xor(ds[it], 16, 64);
    d2 += __shfl_xor(d2, 32, 64);
#pragma unroll
    for (int r = 0; r < 4; ++r)
      inv[it][r] = 1.0f / fmaxf(__shfl(d2, quad * 4 + r, 64), 1e-30f);
  }

#pragma unroll
  for (int it = 0; it < 2; ++it) {
#pragma unroll
    for (int dt = 0; dt < 4; ++dt) {
#pragma unroll
      for (int r = 0; r < 4; ++r) {
        int row = i0 + it * 16 + quad * 4 + r;
        int col = w * 64 + dt * 16 + ln;
        out[(size_t)(b * N_ + row) * 256 + col] = acc[it][dt][r] * inv[it][r];
      }
    }
  }
}

// ================= cooperative fallback (R5, verbatim; safety net) =================
__global__ __launch_bounds__(256) void k_gat(const float* x, const int* adj,
                                             const float* W, const float* a_src,
                                             const float* a_dst, float* out) {
  __shared__ float xls[IND * 8];
  __shared__ float e_lds[H_][N_];
  __shared__ float es_lds2[H_][64];
  __shared__ unsigned int adj_lds2[64 * 33];

  const int g = blockIdx.x, t = threadIdx.x, l = t & 63, wv = t >> 6;
  unsigned short* hT = reinterpret_cast<unsigned short*>(out);
  float* e_srcT = out + 2097152;
  float* e_dstT = out + 2162688;
  unsigned int* adjb = reinterpret_cast<unsigned int*>(out + 2228224);

#pragma unroll 4
  for (int q = 0; q < 16; ++q) {
    int f = g * 4096 + q * 256 + t;
    unsigned long long m = __ballot(adj[f] > 0);
    if (l == 0) { adjb[f >> 5] = (unsigned int)m; adjb[(f >> 5) + 1] = (unsigned int)(m >> 32); }
  }
  const int hh = wv, d = l;
  const float asv = a_src[t], adv = a_dst[t];
  for (int u = 0; u < 8; ++u) {
    const int vb = g * 8 + u, b = vb >> 7, n0 = (vb & 127) * 8;
    {
      const float4v v = reinterpret_cast<const float4v*>(x + (size_t)(b * N_ + n0) * IND)[t];
      int e0 = t * 4, r = e0 >> 7, k = e0 & 127;
      float* dst = &xls[k * 8 + r];
      dst[0] = v.x; dst[8] = v.y; dst[16] = v.z; dst[24] = v.w;
    }
    __syncthreads();
    float acc[8] = {0.f, 0.f, 0.f, 0.f, 0.f, 0.f, 0.f, 0.f};
#pragma unroll 4
    for (int k = 0; k < IND; ++k) {
      float wval = W[k * 256 + t];
      const float4v x0 = *reinterpret_cast<const float4v*>(&xls[k * 8]);
      const float4v x1 = *reinterpret_cast<const float4v*>(&xls[k * 8 + 4]);
      acc[0] += x0.x * wval; acc[1] += x0.y * wval; acc[2] += x0.z * wval; acc[3] += x0.w * wval;
      acc[4] += x1.x * wval; acc[5] += x1.y * wval; acc[6] += x1.z * wval; acc[7] += x1.w * wval;
    }
    short8 hs;
#pragma unroll
    for (int r = 0; r < 8; ++r) hs[r] = (short)f2bf(acc[r]);
    *reinterpret_cast<short8*>(hT + ((size_t)(b * H_ + hh) * D_ + d) * N_ + n0) = hs;
#pragma unroll
    for (int r = 0; r < 8; ++r) {
      float es = acc[r] * asv, ed = acc[r] * adv;
#pragma unroll
      for (int m = 1; m < 64; m <<= 1) { es += __shfl_xor(es, m, 64); ed += __shfl_xor(ed, m, 64); }
      if (d == 0) {
        e_srcT[(b * H_ + hh) * N_ + n0 + r] = es;
        e_dstT[(b * H_ + hh) * N_ + n0 + r] = ed;
      }
    }
    __syncthreads();
  }
  cg::this_grid().sync();
  const int w = wv, quad = l >> 4, ln = l & 15, b = g >> 4, i0 = (g & 15) * 64;
#pragma unroll
  for (int q = 0; q < 8; ++q) {
    int idx = q * 256 + t, r = idx >> 5, c2 = idx & 31;
    adj_lds2[r * 33 + c2] = adjb[(i0 + r) * 32 + c2];
  }
  {
    const float4v* src = reinterpret_cast<const float4v*>(e_dstT + (size_t)(b * H_ + w) * N_);
    float4v* dst = reinterpret_cast<float4v*>(&e_lds[w][0]);
#pragma unroll
    for (int q = 0; q < 4; ++q) dst[q * 64 + l] = src[q * 64 + l];
    es_lds2[w][l] = e_srcT[(size_t)(b * H_ + w) * N_ + i0 + l];
  }
  __syncthreads();
  float c[4];
#pragma unroll
  for (int it = 0; it < 4; ++it) c[it] = es_lds2[w][it * 16 + ln];
  const unsigned short* slab = hT + (size_t)(b * H_ + w) * D_ * N_;
  const unsigned short* hb = slab + ln * N_;
  float4v acc[4][4];
#pragma unroll
  for (int it = 0; it < 4; ++it)
#pragma unroll
    for (int dt = 0; dt < 4; ++dt) acc[it][dt] = (float4v){0.f, 0.f, 0.f, 0.f};
  float ds[4] = {0.f, 0.f, 0.f, 0.f};
  for (int j0 = 0; j0 < N_; j0 += 32) {
    const float* ep = &e_lds[w][j0 + quad * 8];
    float4v e0 = *reinterpret_cast<const float4v*>(ep);
    float4v e1 = *reinterpret_cast<const float4v*>(ep + 4);
    float ej[8] = {e0.x, e0.y, e0.z, e0.w, e1.x, e1.y, e1.z, e1.w};
    unsigned int aw[4];
#pragma unroll
    for (int it = 0; it < 4; ++it) aw[it] = adj_lds2[(it * 16 + ln) * 33 + (j0 >> 5)];
    short8 afr[4];
#pragma unroll
    for (int it = 0; it < 4; ++it) {
#pragma unroll
      for (int jj = 0; jj < 8; ++jj) {
        float s = c[it] + ej[jj];
        s = fmaxf(s, NEG * s); s = fminf(s, 30.f);
        float p = ((aw[it] >> (quad * 8 + jj)) & 1u) ? __expf(s) : 0.f;
        ds[it] += p; afr[it][jj] = (short)f2bf(p);
      }
    }
#pragma unroll
    for (int dt = 0; dt < 4; ++dt) {
      short8 bv = *reinterpret_cast<const short8*>(hb + dt * 16 * N_ + j0 + quad * 8);
#pragma unroll
      for (int it = 0; it < 4; ++it)
        acc[it][dt] = __builtin_amdgcn_mfma_f32_16x16x32_bf16(afr[it], bv, acc[it][dt], 0, 0, 0);
    }
  }
  float inv[4][4];
#pragma unroll
  for (int it = 0; it < 4; ++it) {
    float d2 = ds[it] + __shfl_xor(ds[it], 16, 64);
    d2 += __shfl_xor(d2, 32, 64);
#pragma unroll
    for (int r = 0; r < 4; ++r) inv[it][r] = 1.0f / fmaxf(__shfl(d2, quad * 4 + r, 64), 1e-30f);
  }
  cg::this_grid().sync();
#pragma unroll
  for (int it = 0; it < 4; ++it)
#pragma unroll
    for (int dt = 0; dt < 4; ++dt)
#pragma unroll
      for (int r = 0; r < 4; ++r) {
        int row = i0 + it * 16 + quad * 4 + r, col = w * 64 + dt * 16 + ln;
        out[(size_t)(b * N_ + row) * 256 + col] = acc[it][dt][r] * inv[it][r];
      }
}

extern "C" void kernel_launch(void* const* d_in, const int* in_sizes, int n_in,
                              void* d_out, int out_size, void* d_ws, size_t ws_size,
                              hipStream_t stream) {
  const float* x = (const float*)d_in[0];
  const int* adj = (const int*)d_in[1];
  const float* W = (const float*)d_in[2];
  const float* a_src = (const float*)d_in[3];
  const float* a_dst = (const float*)d_in[4];
  float* outp = (float*)d_out;

  if (ws_size >= 9109504u) {
    char* ws = (char*)d_ws;
    unsigned short* hT = (unsigned short*)ws;
    float* e_srcT = (float*)(ws + 8388608);
    float* e_dstT = (float*)(ws + 8650752);
    unsigned int* adjb = (unsigned int*)(ws + 8912896);
    unsigned short* wT = (unsigned short*)(ws + 9043968);
    hipLaunchKernelGGL(k_prep, dim3(4128), dim3(256), 0, stream, adj, W, adjb, wT);
    hipLaunchKernelGGL(k_proj, dim3(512), dim3(256), 0, stream,
                       x, a_src, a_dst, wT, hT, e_srcT, e_dstT);
    hipLaunchKernelGGL(k_attn, dim3(512), dim3(256), 0, stream,
                       hT, e_srcT, e_dstT, adjb, outp);
  } else {
    void* args[] = {(void*)&x, (void*)&adj, (void*)&W, (void*)&a_src, (void*)&a_dst, (void*)&outp};
    hipLaunchCooperativeKernel((void*)k_gat, dim3(256), dim3(256), args, 0u, stream);
  }
}

// Round 12
// 104.139 us; speedup vs baseline: 1.2257x; 1.2257x over previous
//
#include <hip/hip_runtime.h>
#include <hip/hip_cooperative_groups.h>

namespace cg = cooperative_groups;

// GAT layer: B=16, N=1024, IN_DIM=128, H=4, D=64, neg_slope=0.2
// Inputs fp32, adj int32, out fp32.
//
// R12: k_prep + k_proj = R9 verbatim (HW-proven). k_attn = R11's
// factored-exp math (HW-proven) re-tiled 32->16 rows/block:
// 1024 blocks -> 4 blocks/CU -> 4 waves/SIMD (was 2) to hide the
// F1/F2 LDS-read latency that made R11 regress. No j-split (the
// R8/R10 512-thread combine structure remains quarantined).
// ws: hT @0 (8MB) | e_srcT @8388608 | e_dstT @8650752 | adjb @8912896 |
//     wT @9043968

#define B_  16
#define N_  1024
#define IND 128
#define H_  4
#define D_  64
#define NEG 0.2f

typedef __attribute__((ext_vector_type(8))) short short8;
typedef __attribute__((ext_vector_type(4))) float float4v;
typedef __attribute__((ext_vector_type(4))) unsigned int uint4v;
typedef __attribute__((ext_vector_type(2))) unsigned int uint2v;

union S8U4 { uint4v u; short8 s; };

static __device__ __forceinline__ unsigned short f2bf(float f) {
  unsigned int u = __float_as_uint(f);
  u += 0x7fffu + ((u >> 16) & 1u);
  return (unsigned short)(u >> 16);
}
static __device__ __forceinline__ unsigned pk_rne(float a, float b) {
  unsigned ua = __float_as_uint(a), ub = __float_as_uint(b);
  ua += 0x7fffu + ((ua >> 16) & 1u);
  ub += 0x7fffu + ((ub >> 16) & 1u);
  return __builtin_amdgcn_perm(ub, ua, 0x07060302);
}

// ---------------- prep: adj bit-pack + W transpose to bf16 (R9) ----------------
__global__ __launch_bounds__(256) void k_prep(const int* __restrict__ adj,
                                              const float* __restrict__ W,
                                              unsigned int* __restrict__ adjb,
                                              unsigned short* __restrict__ wT) {
  const int g = blockIdx.x, t = threadIdx.x, l = t & 63;
  if (g < 4096) {
    int f = g * 256 + t;
    unsigned long long m = __ballot(adj[f] > 0);
    if (l == 0) {
      adjb[f >> 5] = (unsigned int)m;
      adjb[(f >> 5) + 1] = (unsigned int)(m >> 32);
    }
  } else {
    int wb = g - 4096;
#pragma unroll
    for (int i = 0; i < 4; ++i) {
      int k = wb * 4 + i;
      wT[t * 128 + k] = f2bf(W[k * 256 + t]);    // wT[n][k]
    }
  }
}

// ---------------- projection: MFMA GEMM + e dots (R9, proven) ----------------
__global__ __launch_bounds__(256) void k_proj(const float* __restrict__ x,
                                              const float* __restrict__ a_src,
                                              const float* __restrict__ a_dst,
                                              const unsigned short* __restrict__ wT,
                                              unsigned short* __restrict__ hT,
                                              float* __restrict__ e_srcT,
                                              float* __restrict__ e_dstT) {
  __shared__ unsigned short wbuf[128 * 136];
  const int g = blockIdx.x, t = threadIdx.x;
  const int mt = g >> 1, nh = g & 1;
  const int w = t >> 6, l = t & 63, quad = l >> 4, ln = l & 15;

#pragma unroll
  for (int i = 0; i < 8; ++i) {
    int c = i * 256 + t;
    int n = c >> 4, k8 = c & 15;
    *reinterpret_cast<short8*>(&wbuf[n * 136 + k8 * 8]) =
        *reinterpret_cast<const short8*>(wT + (size_t)(nh * 128 + n) * 128 + k8 * 8);
  }
  __syncthreads();

  const int m0 = mt * 64 + w * 16;
  short8 afr[4];
#pragma unroll
  for (int ks = 0; ks < 4; ++ks) {
    const float* xp = x + (size_t)(m0 + ln) * IND + ks * 32 + quad * 8;
    float4v x0 = *reinterpret_cast<const float4v*>(xp);
    float4v x1 = *reinterpret_cast<const float4v*>(xp + 4);
    S8U4 cvt;
    cvt.u = (uint4v){pk_rne(x0.x, x0.y), pk_rne(x0.z, x0.w),
                     pk_rne(x1.x, x1.y), pk_rne(x1.z, x1.w)};
    afr[ks] = cvt.s;
  }

  float4v acc[8];
#pragma unroll
  for (int nf = 0; nf < 8; ++nf) acc[nf] = (float4v){0.f, 0.f, 0.f, 0.f};
#pragma unroll
  for (int nf = 0; nf < 8; ++nf) {
#pragma unroll
    for (int ks = 0; ks < 4; ++ks) {
      short8 bv = *reinterpret_cast<const short8*>(
          &wbuf[(nf * 16 + ln) * 136 + ks * 32 + quad * 8]);
      acc[nf] = __builtin_amdgcn_mfma_f32_16x16x32_bf16(afr[ks], bv, acc[nf], 0, 0, 0);
    }
  }

  const int m_base = m0 + quad * 4;
  const int b = m_base >> 10, nl = m_base & 1023;
  const int jb = nl >> 3, jo = nl & 7;
#pragma unroll
  for (int hl = 0; hl < 2; ++hl) {
    const int h = nh * 2 + hl;
    float es[4] = {0.f, 0.f, 0.f, 0.f}, ed[4] = {0.f, 0.f, 0.f, 0.f};
#pragma unroll
    for (int n4 = 0; n4 < 4; ++n4) {
      int nf = hl * 4 + n4;
      int col = nh * 128 + nf * 16 + ln;
      float asv = a_src[col], adv = a_dst[col];
#pragma unroll
      for (int r = 0; r < 4; ++r) { es[r] += acc[nf][r] * asv; ed[r] += acc[nf][r] * adv; }
      uint2v hv;
      hv.x = pk_rne(acc[nf][0], acc[nf][1]);
      hv.y = pk_rne(acc[nf][2], acc[nf][3]);
      int d = n4 * 16 + ln;
      *reinterpret_cast<uint2v*>(hT + ((size_t)(b * H_ + h) * 128 + jb) * 512 + d * 8 + jo) = hv;
    }
#pragma unroll
    for (int r = 0; r < 4; ++r) {
#pragma unroll
      for (int msk = 1; msk < 16; msk <<= 1) {
        es[r] += __shfl_xor(es[r], msk, 64);
        ed[r] += __shfl_xor(ed[r], msk, 64);
      }
    }
    if (ln == 0) {
#pragma unroll
      for (int r = 0; r < 4; ++r) {
        e_srcT[(b * H_ + h) * N_ + nl + r] = es[r];
        e_dstT[(b * H_ + h) * N_ + nl + r] = ed[r];
      }
    }
  }
}

// ------ attention: 16-row tiles, factored-exp (R11 math, proven) ------
__global__ __launch_bounds__(256) void k_attn(const unsigned short* __restrict__ hT,
                                              const float* __restrict__ e_srcT,
                                              const float* __restrict__ e_dstT,
                                              const unsigned int* __restrict__ adjb,
                                              float* __restrict__ out) {
  __shared__ float F1[H_][N_];                   // exp(e_dst)      16 KB
  __shared__ float F2[H_][N_];                   // exp(0.2 e_dst)  16 KB
  __shared__ float es_lds[H_][16];               // 256 B
  __shared__ unsigned int adj_lds[16 * 33];      // 2.1 KB padded

  const int t = threadIdx.x;
  const int w = t >> 6;                          // head = wave
  const int l = t & 63;
  const int quad = l >> 4;
  const int ln = l & 15;
  const int b = blockIdx.x >> 6;                 // 1024 blocks: 16 b * 64 i-tiles
  const int i0 = (blockIdx.x & 63) * 16;

  // adj bitmask rows i0..i0+15 (512 words, 2/thread)
#pragma unroll
  for (int q = 0; q < 2; ++q) {
    int idx = q * 256 + t;
    adj_lds[(idx >> 5) * 33 + (idx & 31)] = adjb[(i0 + (idx >> 5)) * 32 + (idx & 31)];
  }
  // stage F1/F2 for all heads (each thread: 8 j's x 2 passes)
#pragma unroll
  for (int q = 0; q < 2; ++q) {
    int idx = q * 256 + t;                       // 0..511
    int hidx = idx >> 7, j = (idx & 127) * 8;
    const float* ep = e_dstT + (size_t)(b * H_ + hidx) * N_ + j;
    float4v e0 = *reinterpret_cast<const float4v*>(ep);
    float4v e1 = *reinterpret_cast<const float4v*>(ep + 4);
    *reinterpret_cast<float4v*>(&F1[hidx][j]) =
        (float4v){__expf(e0.x), __expf(e0.y), __expf(e0.z), __expf(e0.w)};
    *reinterpret_cast<float4v*>(&F1[hidx][j + 4]) =
        (float4v){__expf(e1.x), __expf(e1.y), __expf(e1.z), __expf(e1.w)};
    *reinterpret_cast<float4v*>(&F2[hidx][j]) =
        (float4v){__expf(NEG * e0.x), __expf(NEG * e0.y), __expf(NEG * e0.z), __expf(NEG * e0.w)};
    *reinterpret_cast<float4v*>(&F2[hidx][j + 4]) =
        (float4v){__expf(NEG * e1.x), __expf(NEG * e1.y), __expf(NEG * e1.z), __expf(NEG * e1.w)};
  }
  if (l < 16) es_lds[w][l] = e_srcT[(size_t)(b * H_ + w) * N_ + i0 + l];
  __syncthreads();

  // per-row constants (row ln of the 16-row tile)
  const float cc = es_lds[w][ln];
  const float E1 = __expf(cc), E2 = __expf(NEG * cc);

  const unsigned short* slab = hT + (size_t)(b * H_ + w) * 65536;
  const int doff = (quad * 512) + ln * 8;
  float4v acc[4];
#pragma unroll
  for (int dt = 0; dt < 4; ++dt) acc[dt] = (float4v){0.f, 0.f, 0.f, 0.f};
  float ds = 0.f;

  for (int j0 = 0; j0 < N_; j0 += 32) {
    const float* f1p = &F1[w][j0 + quad * 8];
    const float* f2p = &F2[w][j0 + quad * 8];
    float4v f1a = *reinterpret_cast<const float4v*>(f1p);
    float4v f1b = *reinterpret_cast<const float4v*>(f1p + 4);
    float4v f2a = *reinterpret_cast<const float4v*>(f2p);
    float4v f2b = *reinterpret_cast<const float4v*>(f2p + 4);
    float f1[8] = {f1a.x, f1a.y, f1a.z, f1a.w, f1b.x, f1b.y, f1b.z, f1b.w};
    float f2[8] = {f2a.x, f2a.y, f2a.z, f2a.w, f2b.x, f2b.y, f2b.z, f2b.w};
    unsigned int aw = adj_lds[ln * 33 + (j0 >> 5)];
    short8 afr;
#pragma unroll
    for (int jj = 0; jj < 8; ++jj) {
      // exp(lrelu(c+e)) = max(exp(c)exp(e), exp(.2c)exp(.2e)) — exact
      float p = fmaxf(E1 * f1[jj], E2 * f2[jj]);
      p = ((aw >> (quad * 8 + jj)) & 1u) ? p : 0.f;
      ds += p;
      afr[jj] = (short)f2bf(p);
    }
    const unsigned short* jbase = slab + (size_t)(j0 >> 3) * 512;
#pragma unroll
    for (int dt = 0; dt < 4; ++dt) {
      short8 bv = *reinterpret_cast<const short8*>(jbase + doff + dt * 128);
      acc[dt] = __builtin_amdgcn_mfma_f32_16x16x32_bf16(afr, bv, acc[dt], 0, 0, 0);
    }
  }

  float d2 = ds + __shfl_xor(ds, 16, 64);
  d2 += __shfl_xor(d2, 32, 64);
  float inv[4];
#pragma unroll
  for (int r = 0; r < 4; ++r)
    inv[r] = 1.0f / fmaxf(__shfl(d2, quad * 4 + r, 64), 1e-30f);

#pragma unroll
  for (int dt = 0; dt < 4; ++dt) {
#pragma unroll
    for (int r = 0; r < 4; ++r) {
      int row = i0 + quad * 4 + r;               // C-layout: row=quad*4+reg, col=ln
      int col = w * 64 + dt * 16 + ln;
      out[(size_t)(b * N_ + row) * 256 + col] = acc[dt][r] * inv[r];
    }
  }
}

// ================= cooperative fallback (R5, verbatim; safety net) =================
__global__ __launch_bounds__(256) void k_gat(const float* x, const int* adj,
                                             const float* W, const float* a_src,
                                             const float* a_dst, float* out) {
  __shared__ float xls[IND * 8];
  __shared__ float e_lds[H_][N_];
  __shared__ float es_lds2[H_][64];
  __shared__ unsigned int adj_lds2[64 * 33];

  const int g = blockIdx.x, t = threadIdx.x, l = t & 63, wv = t >> 6;
  unsigned short* hT = reinterpret_cast<unsigned short*>(out);
  float* e_srcT = out + 2097152;
  float* e_dstT = out + 2162688;
  unsigned int* adjb = reinterpret_cast<unsigned int*>(out + 2228224);

#pragma unroll 4
  for (int q = 0; q < 16; ++q) {
    int f = g * 4096 + q * 256 + t;
    unsigned long long m = __ballot(adj[f] > 0);
    if (l == 0) { adjb[f >> 5] = (unsigned int)m; adjb[(f >> 5) + 1] = (unsigned int)(m >> 32); }
  }
  const int hh = wv, d = l;
  const float asv = a_src[t], adv = a_dst[t];
  for (int u = 0; u < 8; ++u) {
    const int vb = g * 8 + u, b = vb >> 7, n0 = (vb & 127) * 8;
    {
      const float4v v = reinterpret_cast<const float4v*>(x + (size_t)(b * N_ + n0) * IND)[t];
      int e0 = t * 4, r = e0 >> 7, k = e0 & 127;
      float* dst = &xls[k * 8 + r];
      dst[0] = v.x; dst[8] = v.y; dst[16] = v.z; dst[24] = v.w;
    }
    __syncthreads();
    float acc[8] = {0.f, 0.f, 0.f, 0.f, 0.f, 0.f, 0.f, 0.f};
#pragma unroll 4
    for (int k = 0; k < IND; ++k) {
      float wval = W[k * 256 + t];
      const float4v x0 = *reinterpret_cast<const float4v*>(&xls[k * 8]);
      const float4v x1 = *reinterpret_cast<const float4v*>(&xls[k * 8 + 4]);
      acc[0] += x0.x * wval; acc[1] += x0.y * wval; acc[2] += x0.z * wval; acc[3] += x0.w * wval;
      acc[4] += x1.x * wval; acc[5] += x1.y * wval; acc[6] += x1.z * wval; acc[7] += x1.w * wval;
    }
    short8 hs;
#pragma unroll
    for (int r = 0; r < 8; ++r) hs[r] = (short)f2bf(acc[r]);
    *reinterpret_cast<short8*>(hT + ((size_t)(b * H_ + hh) * D_ + d) * N_ + n0) = hs;
#pragma unroll
    for (int r = 0; r < 8; ++r) {
      float es = acc[r] * asv, ed = acc[r] * adv;
#pragma unroll
      for (int m = 1; m < 64; m <<= 1) { es += __shfl_xor(es, m, 64); ed += __shfl_xor(ed, m, 64); }
      if (d == 0) {
        e_srcT[(b * H_ + hh) * N_ + n0 + r] = es;
        e_dstT[(b * H_ + hh) * N_ + n0 + r] = ed;
      }
    }
    __syncthreads();
  }
  cg::this_grid().sync();
  const int w = wv, quad = l >> 4, ln = l & 15, b = g >> 4, i0 = (g & 15) * 64;
#pragma unroll
  for (int q = 0; q < 8; ++q) {
    int idx = q * 256 + t, r = idx >> 5, c2 = idx & 31;
    adj_lds2[r * 33 + c2] = adjb[(i0 + r) * 32 + c2];
  }
  {
    const float4v* src = reinterpret_cast<const float4v*>(e_dstT + (size_t)(b * H_ + w) * N_);
    float4v* dst = reinterpret_cast<float4v*>(&e_lds[w][0]);
#pragma unroll
    for (int q = 0; q < 4; ++q) dst[q * 64 + l] = src[q * 64 + l];
    es_lds2[w][l] = e_srcT[(size_t)(b * H_ + w) * N_ + i0 + l];
  }
  __syncthreads();
  float c[4];
#pragma unroll
  for (int it = 0; it < 4; ++it) c[it] = es_lds2[w][it * 16 + ln];
  const unsigned short* slab = hT + (size_t)(b * H_ + w) * D_ * N_;
  const unsigned short* hb = slab + ln * N_;
  float4v acc[4][4];
#pragma unroll
  for (int it = 0; it < 4; ++it)
#pragma unroll
    for (int dt = 0; dt < 4; ++dt) acc[it][dt] = (float4v){0.f, 0.f, 0.f, 0.f};
  float ds[4] = {0.f, 0.f, 0.f, 0.f};
  for (int j0 = 0; j0 < N_; j0 += 32) {
    const float* ep = &e_lds[w][j0 + quad * 8];
    float4v e0 = *reinterpret_cast<const float4v*>(ep);
    float4v e1 = *reinterpret_cast<const float4v*>(ep + 4);
    float ej[8] = {e0.x, e0.y, e0.z, e0.w, e1.x, e1.y, e1.z, e1.w};
    unsigned int aw[4];
#pragma unroll
    for (int it = 0; it < 4; ++it) aw[it] = adj_lds2[(it * 16 + ln) * 33 + (j0 >> 5)];
    short8 afr[4];
#pragma unroll
    for (int it = 0; it < 4; ++it) {
#pragma unroll
      for (int jj = 0; jj < 8; ++jj) {
        float s = c[it] + ej[jj];
        s = fmaxf(s, NEG * s); s = fminf(s, 30.f);
        float p = ((aw[it] >> (quad * 8 + jj)) & 1u) ? __expf(s) : 0.f;
        ds[it] += p; afr[it][jj] = (short)f2bf(p);
      }
    }
#pragma unroll
    for (int dt = 0; dt < 4; ++dt) {
      short8 bv = *reinterpret_cast<const short8*>(hb + dt * 16 * N_ + j0 + quad * 8);
#pragma unroll
      for (int it = 0; it < 4; ++it)
        acc[it][dt] = __builtin_amdgcn_mfma_f32_16x16x32_bf16(afr[it], bv, acc[it][dt], 0, 0, 0);
    }
  }
  float inv[4][4];
#pragma unroll
  for (int it = 0; it < 4; ++it) {
    float d2 = ds[it] + __shfl_xor(ds[it], 16, 64);
    d2 += __shfl_xor(d2, 32, 64);
#pragma unroll
    for (int r = 0; r < 4; ++r) inv[it][r] = 1.0f / fmaxf(__shfl(d2, quad * 4 + r, 64), 1e-30f);
  }
  cg::this_grid().sync();
#pragma unroll
  for (int it = 0; it < 4; ++it)
#pragma unroll
    for (int dt = 0; dt < 4; ++dt)
#pragma unroll
      for (int r = 0; r < 4; ++r) {
        int row = i0 + it * 16 + quad * 4 + r, col = w * 64 + dt * 16 + ln;
        out[(size_t)(b * N_ + row) * 256 + col] = acc[it][dt][r] * inv[it][r];
      }
}

extern "C" void kernel_launch(void* const* d_in, const int* in_sizes, int n_in,
                              void* d_out, int out_size, void* d_ws, size_t ws_size,
                              hipStream_t stream) {
  const float* x = (const float*)d_in[0];
  const int* adj = (const int*)d_in[1];
  const float* W = (const float*)d_in[2];
  const float* a_src = (const float*)d_in[3];
  const float* a_dst = (const float*)d_in[4];
  float* outp = (float*)d_out;

  if (ws_size >= 9109504u) {
    char* ws = (char*)d_ws;
    unsigned short* hT = (unsigned short*)ws;
    float* e_srcT = (float*)(ws + 8388608);
    float* e_dstT = (float*)(ws + 8650752);
    unsigned int* adjb = (unsigned int*)(ws + 8912896);
    unsigned short* wT = (unsigned short*)(ws + 9043968);
    hipLaunchKernelGGL(k_prep, dim3(4128), dim3(256), 0, stream, adj, W, adjb, wT);
    hipLaunchKernelGGL(k_proj, dim3(512), dim3(256), 0, stream,
                       x, a_src, a_dst, wT, hT, e_srcT, e_dstT);
    hipLaunchKernelGGL(k_attn, dim3(1024), dim3(256), 0, stream,
                       hT, e_srcT, e_dstT, adjb, outp);
  } else {
    void* args[] = {(void*)&x, (void*)&adj, (void*)&W, (void*)&a_src, (void*)&a_dst, (void*)&outp};
    hipLaunchCooperativeKernel((void*)k_gat, dim3(256), dim3(256), args, 0u, stream);
  }
}